// Round 2
// baseline (1044.941 us; speedup 1.0000x reference)
//
#include <hip/hip_runtime.h>
#include <math.h>

#define BLOCK 256
#define CAP 512
#define WSEG 128
#define KTOP 100
#define TEMP 5.0f
#define LAMBDA_TCS 10.0f
#define IGNORE_INDEX (-100)
#define SPEC_TH 2.5f      // speculative top-k floor; exact fallback if it fails
#define PAD_NEG (-1.0e30f)
#define NHIST 512

// Monotonic float->uint mapping: order-preserving for all finite floats.
__device__ __forceinline__ unsigned key_of(float f) {
    unsigned u = __float_as_uint(f);
    return u ^ ((unsigned)((int)u >> 31) | 0x80000000u);
}

// popcount of mask restricted to lanes below this lane (wave64-correct).
__device__ __forceinline__ int prefix_count(unsigned long long mask) {
    return __builtin_amdgcn_mbcnt_hi((unsigned)(mask >> 32),
           __builtin_amdgcn_mbcnt_lo((unsigned)mask, 0));
}

// Online logsumexp accumulate: ONE transcendental per element.
// d=v-m; e=exp(-|d|); if d>0 (new max): s=s*e+1, m=v; else s+=e.
// m=-inf start: d=+inf -> e=0, s=1, m=v. PAD_NEG elements are absorbed exactly.
__device__ __forceinline__ void lse_acc(float& m, float& s, float v) {
    float d = v - m;
    float e = __expf(-fabsf(d));
    float up = __fmaf_rn(s, e, 1.0f);
    float dn = s + e;
    bool g = d > 0.0f;
    s = g ? up : dn;
    m = g ? v : m;
}

__device__ __forceinline__ float block_sum(float v, float* red) {
    for (int off = 32; off; off >>= 1) v += __shfl_down(v, off);
    __syncthreads();
    if ((threadIdx.x & 63) == 0) red[threadIdx.x >> 6] = v;
    __syncthreads();
    return red[0] + red[1] + red[2] + red[3];
}
__device__ __forceinline__ float block_max(float v, float* red) {
    for (int off = 32; off; off >>= 1) v = fmaxf(v, __shfl_down(v, off));
    __syncthreads();
    if ((threadIdx.x & 63) == 0) red[threadIdx.x >> 6] = v;
    __syncthreads();
    return fmaxf(fmaxf(red[0], red[1]), fmaxf(red[2], red[3]));
}

// Wave-synchronous candidate collection: no atomics, no LDS round-trips.
// wcnt is wave-uniform (ballot-derived); ds_write is fire-and-forget.
#define COLLECT(v, idx)                                                   \
    do {                                                                  \
        bool pass_ = (v) >= SPEC_TH;                                      \
        unsigned long long mk_ = __ballot(pass_);                         \
        if (mk_) {                                                        \
            int pos_ = wcnt + prefix_count(mk_);                          \
            if (pass_ && pos_ < WSEG) {                                   \
                segVal[wbase + pos_] = (v);                               \
                segIdx[wbase + pos_] = (idx);                             \
            }                                                             \
            wcnt += __popcll(mk_);                                        \
        }                                                                 \
    } while (0)

// Per-float4 pre-gate: one any-check skips 4 ballots in the common case.
#define COLLECT4(tv, base)                                                \
    do {                                                                  \
        float mx_ = fmaxf(fmaxf((tv).x, (tv).y), fmaxf((tv).z, (tv).w)); \
        if (__any(mx_ >= SPEC_TH)) {                                      \
            COLLECT((tv).x, (base));                                      \
            COLLECT((tv).y, (base) + 1);                                  \
            COLLECT((tv).z, (base) + 2);                                  \
            COLLECT((tv).w, (base) + 3);                                  \
        }                                                                 \
    } while (0)

__global__ __launch_bounds__(BLOCK, 8) void tcs_main(
    const float* __restrict__ S, const float* __restrict__ T,
    const int* __restrict__ L, float* __restrict__ acc, int V, int tokens)
{
    const int tok = blockIdx.x;
    if (tok >= tokens) return;
    const int tid = threadIdx.x;
    const int lane = tid & 63;
    const int wid = tid >> 6;
    const int wbase = wid * WSEG;
    const size_t row = (size_t)tok * (size_t)V;
    const float* srow = S + row;
    const float* trow = T + row;

    __shared__ float segVal[4 * WSEG];
    __shared__ int   segIdx[4 * WSEG];
    __shared__ float candVal[CAP];
    __shared__ int   candIdx[CAP];
    __shared__ float selVal[128];
    __shared__ int   selIdx[128];
    __shared__ unsigned hist[NHIST];   // exact-fallback only
    __shared__ unsigned chunk[64];     // exact-fallback only
    __shared__ float red[4], redM[4], redS[4];
    __shared__ int s_wcnt[4];
    __shared__ int s_candCount, s_selCount;
    __shared__ unsigned s_lowBound, s_countGE, s_cGT;
    __shared__ int s_shift;

    // Early label fetch (latency hidden under pass A).
    int lab = 0; bool valid = false; float sl = 0.0f;
    if (tid == 0) {
        lab = L[tok];
        valid = (lab != IGNORE_INDEX);
        if (valid && lab >= 0 && lab < V) sl = srow[lab];
    }

    // ---- Pass A: student online LSE (4 indep accumulators) + teacher
    //      wave-compacted speculative candidate collection.
    float m0 = -INFINITY, m1 = -INFINITY, m2 = -INFINITY, m3 = -INFINITY;
    float s0 = 0.f, s1 = 0.f, s2 = 0.f, s3 = 0.f;
    int wcnt = 0;                       // wave-uniform candidate count
    const int V4 = V >> 2;
    const float4* s4 = (const float4*)srow;
    const float4* t4 = (const float4*)trow;

    const int NFULL = V4 / (4 * BLOCK);  // full 8-load batches (uniform)
#pragma unroll 1
    for (int b = 0; b < NFULL; ++b) {
        int i = b * 4 * BLOCK + tid;
        float4 sa = s4[i];
        float4 sb = s4[i + BLOCK];
        float4 sc = s4[i + 2 * BLOCK];
        float4 sd = s4[i + 3 * BLOCK];
        float4 ta = t4[i];
        float4 tb = t4[i + BLOCK];
        float4 tc = t4[i + 2 * BLOCK];
        float4 td = t4[i + 3 * BLOCK];
        lse_acc(m0, s0, sa.x); lse_acc(m1, s1, sa.y); lse_acc(m2, s2, sa.z); lse_acc(m3, s3, sa.w);
        lse_acc(m0, s0, sb.x); lse_acc(m1, s1, sb.y); lse_acc(m2, s2, sb.z); lse_acc(m3, s3, sb.w);
        lse_acc(m0, s0, sc.x); lse_acc(m1, s1, sc.y); lse_acc(m2, s2, sc.z); lse_acc(m3, s3, sc.w);
        lse_acc(m0, s0, sd.x); lse_acc(m1, s1, sd.y); lse_acc(m2, s2, sd.z); lse_acc(m3, s3, sd.w);
        COLLECT4(ta, i << 2);
        COLLECT4(tb, (i + BLOCK) << 2);
        COLLECT4(tc, (i + 2 * BLOCK) << 2);
        COLLECT4(td, (i + 3 * BLOCK) << 2);
    }
    // float4 tail: uniform trip count, OOB lanes padded so ballots stay full-wave.
    {
        const int T0 = NFULL * 4 * BLOCK;
        const int tail = V4 - T0;
        const int tIter = (tail + BLOCK - 1) / BLOCK;
#pragma unroll 1
        for (int t = 0; t < tIter; ++t) {
            int i = T0 + t * BLOCK + tid;
            bool inb = i < V4;
            float4 sv, tv;
            if (inb) { sv = s4[i]; tv = t4[i]; }
            else     { sv = make_float4(PAD_NEG, PAD_NEG, PAD_NEG, PAD_NEG); tv = sv; }
            lse_acc(m0, s0, sv.x); lse_acc(m1, s1, sv.y); lse_acc(m2, s2, sv.z); lse_acc(m3, s3, sv.w);
            COLLECT4(tv, i << 2);
        }
    }
    // scalar remainder (V % 4): at most one uniform iteration.
    {
        const int rb = V4 << 2;
        if (rb < V) {
            int j = rb + tid;
            bool inb = j < V;
            float sv = inb ? srow[j] : PAD_NEG;
            float tv = inb ? trow[j] : PAD_NEG;
            lse_acc(m0, s0, sv);
            COLLECT(tv, j);
        }
    }

    if (lane == 0) s_wcnt[wid] = wcnt;

    // merge the 4 accumulators, then wave + block reduce
    {
        float mn = fmaxf(m0, m1); s0 = s0 * __expf(m0 - mn) + s1 * __expf(m1 - mn); m0 = mn;
        mn = fmaxf(m2, m3);       s2 = s2 * __expf(m2 - mn) + s3 * __expf(m3 - mn); m2 = mn;
        mn = fmaxf(m0, m2);       s0 = s0 * __expf(m0 - mn) + s2 * __expf(m2 - mn); m0 = mn;
    }
    for (int off = 32; off; off >>= 1) {
        float mo = __shfl_down(m0, off);
        float so = __shfl_down(s0, off);
        float mn = fmaxf(m0, mo);
        s0 = s0 * __expf(m0 - mn) + so * __expf(mo - mn);
        m0 = mn;
    }
    if ((tid & 63) == 0) { redM[tid >> 6] = m0; redS[tid >> 6] = s0; }
    __syncthreads();   // closes seg writes + s_wcnt + redM/redS

    float nll = 0.0f;
    if (tid == 0) {
        float mm = redM[0], ss = redS[0];
        for (int w = 1; w < 4; ++w) {
            float mn = fmaxf(mm, redM[w]);
            ss = ss * __expf(mm - mn) + redS[w] * __expf(redM[w] - mn);
            mm = mn;
        }
        nll = (mm + __logf(ss)) - sl;   // -log_softmax at label
    }

    const int c0 = s_wcnt[0], c1 = s_wcnt[1], c2 = s_wcnt[2], c3 = s_wcnt[3];
    const int total = c0 + c1 + c2 + c3;
    const bool fast = (total >= KTOP) &&
                      (c0 <= WSEG) && (c1 <= WSEG) && (c2 <= WSEG) && (c3 <= WSEG);

    if (fast) {
        // compact per-wave segments into a contiguous candidate list
        int myoff = 0;
        for (int u = 0; u < wid; ++u) myoff += s_wcnt[u];
        const int mycnt = s_wcnt[wid];
        for (int r = lane; r < mycnt; r += 64) {
            candVal[myoff + r] = segVal[wbase + r];
            candIdx[myoff + r] = segIdx[wbase + r];
        }
        if (tid == 0) s_candCount = total;
        __syncthreads();
    } else {
        // ---- exact radix-select fallback (arbitrary data) ----
        for (int b = tid; b < NHIST; b += BLOCK) hist[b] = 0;
        if (tid == 0) s_candCount = 0;
        __syncthreads();
        for (int p = tid; p < V; p += BLOCK)
            atomicAdd(&hist[key_of(trow[p]) >> 23], 1u);
        __syncthreads();
        if (tid < 64) {
            unsigned cs = 0;
            for (int b = tid * 8; b < tid * 8 + 8; ++b) cs += hist[b];
            chunk[tid] = cs;
        }
        __syncthreads();
        if (tid == 0) {
            unsigned accum = 0; int csel = 0;
            for (int c = 63; c >= 0; --c) {
                if (accum + chunk[c] >= (unsigned)KTOP) { csel = c; break; }
                accum += chunk[c];
            }
            int bsel = csel * 8;
            for (int b = csel * 8 + 7; b >= csel * 8; --b) {
                if (accum + hist[b] >= (unsigned)KTOP) { bsel = b; break; }
                accum += hist[b];
            }
            s_cGT = accum;
            s_countGE = accum + hist[bsel];
            s_lowBound = (unsigned)bsel << 23;
            s_shift = 23;
        }
        while (true) {
            __syncthreads();
            if (s_countGE <= (unsigned)CAP || s_shift == 0) break;
            const int shift = s_shift;
            const int nextShift = (shift >= 9) ? (shift - 9) : 0;
            const int nb = 1 << (shift - nextShift);
            const unsigned prefix = s_lowBound >> shift;
            const unsigned cGT_in = s_cGT;
            __syncthreads();
            for (int b = tid; b < nb; b += BLOCK) hist[b] = 0;
            __syncthreads();
            for (int p = tid; p < V; p += BLOCK) {
                unsigned key = key_of(trow[p]);
                if ((key >> shift) == prefix)
                    atomicAdd(&hist[(key >> nextShift) & (nb - 1)], 1u);
            }
            __syncthreads();
            if (tid == 0) {
                unsigned kRem = (unsigned)KTOP - cGT_in;
                unsigned accum = 0; int bsel = 0;
                for (int b = nb - 1; b >= 0; --b) {
                    if (accum + hist[b] >= kRem) { bsel = b; break; }
                    accum += hist[b];
                }
                s_cGT = cGT_in + accum;
                s_countGE = s_cGT + hist[bsel];
                s_lowBound |= (unsigned)bsel << nextShift;
                s_shift = nextShift;
            }
        }
        __syncthreads();
        const unsigned lowB = s_lowBound;
        for (int p = tid; p < V; p += BLOCK) {
            float v = trow[p];
            if (key_of(v) >= lowB) {
                int q = atomicAdd(&s_candCount, 1);
                if (q < CAP) { candVal[q] = v; candIdx[q] = p; }
            }
        }
        __syncthreads();
    }

    // ---- exact top-K among M candidates via O(M^2) ranking (idx tie-break) ----
    const int M = min(s_candCount, CAP);
    if (tid == 0) s_selCount = 0;
    __syncthreads();
    for (int c = tid; c < M; c += BLOCK) {
        float vc = candVal[c]; int ic = candIdx[c];
        int rank = 0;
        for (int j = 0; j < M; ++j) {
            float vj = candVal[j]; int ij = candIdx[j];
            if (vj > vc || (vj == vc && ij < ic)) ++rank;
        }
        if (rank < KTOP) {
            int p = atomicAdd(&s_selCount, 1);
            if (p < 128) { selVal[p] = vc; selIdx[p] = ic; }
        }
    }
    __syncthreads();
    const int n = min(s_selCount, 128);

    // ---- temperature KL over the selected top-K ----
    float x = -INFINITY, y = -INFINITY;
    if (tid < n) {
        x = selVal[tid] * (1.0f / TEMP);
        y = srow[selIdx[tid]] * (1.0f / TEMP);
    }
    float mx = block_max(x, red);
    float my = block_max(y, red);
    float ex = (tid < n) ? __expf(x - mx) : 0.0f;
    float Zt = block_sum(ex, red);
    float ey = (tid < n) ? __expf(y - my) : 0.0f;
    float Zs = block_sum(ey, red);
    float lZt = __logf(Zt), lZs = __logf(Zs);
    float kli = (tid < n) ? (ex / Zt) * ((x - mx - lZt) - (y - my - lZs)) : 0.0f;
    float kl = block_sum(kli, red);

    if (tid == 0 && valid) {
        atomicAdd(&acc[0], nll);
        atomicAdd(&acc[1], kl);
        atomicAdd(&acc[2], 1.0f);
    }
}

__global__ void tcs_finalize(const float* __restrict__ acc, float* __restrict__ out) {
    float cnt = fmaxf(acc[2], 1.0f);
    float ce = acc[0] / cnt;
    float tcs = acc[1] / cnt * (TEMP * TEMP);
    out[0] = ce + LAMBDA_TCS * tcs;
    out[1] = ce;
    out[2] = tcs;
    out[3] = 0.0f;
}

extern "C" void kernel_launch(void* const* d_in, const int* in_sizes, int n_in,
                              void* d_out, int out_size, void* d_ws, size_t ws_size,
                              hipStream_t stream) {
    const float* S = (const float*)d_in[0];
    const float* T = (const float*)d_in[1];
    const int* L = (const int*)d_in[2];
    const int tokens = in_sizes[2];
    const int V = in_sizes[0] / tokens;
    float* acc = (float*)d_ws;
    hipMemsetAsync(acc, 0, 4 * sizeof(float), stream);
    tcs_main<<<tokens, BLOCK, 0, stream>>>(S, T, L, acc, V, tokens);
    tcs_finalize<<<1, 1, 0, stream>>>(acc, (float*)d_out);
}

// Round 3
// 1023.824 us; speedup vs baseline: 1.0206x; 1.0206x over previous
//
#include <hip/hip_runtime.h>
#include <math.h>

#define BLOCK 256
#define CAP 512
#define SLOTS 8
#define KTOP 100
#define TEMP 5.0f
#define LAMBDA_TCS 10.0f
#define IGNORE_INDEX (-100)
#define SPEC_TH 2.5f      // speculative top-k floor; exact fallback if it fails
#define NHIST 512

// Monotonic float->uint mapping: order-preserving for all finite floats.
__device__ __forceinline__ unsigned key_of(float f) {
    unsigned u = __float_as_uint(f);
    return u ^ ((unsigned)((int)u >> 31) | 0x80000000u);
}

__device__ __forceinline__ float block_sum(float v, float* red) {
    for (int off = 32; off; off >>= 1) v += __shfl_down(v, off);
    __syncthreads();
    if ((threadIdx.x & 63) == 0) red[threadIdx.x >> 6] = v;
    __syncthreads();
    return red[0] + red[1] + red[2] + red[3];
}
__device__ __forceinline__ float block_max(float v, float* red) {
    for (int off = 32; off; off >>= 1) v = fmaxf(v, __shfl_down(v, off));
    __syncthreads();
    if ((threadIdx.x & 63) == 0) red[threadIdx.x >> 6] = v;
    __syncthreads();
    return fmaxf(fmaxf(red[0], red[1]), fmaxf(red[2], red[3]));
}

__global__ __launch_bounds__(BLOCK, 8) void tcs_main(
    const float* __restrict__ S, const float* __restrict__ T,
    const int* __restrict__ L, float* __restrict__ acc, int V, int tokens)
{
    const int tok = blockIdx.x;
    if (tok >= tokens) return;
    const int tid = threadIdx.x;
    const int lane = tid & 63;
    const int wid = tid >> 6;
    const size_t row = (size_t)tok * (size_t)V;
    const float* srow = S + row;
    const float* trow = T + row;

    // 16 KB per-thread stash; aliased as hist/chunk in the exact fallback.
    __shared__ unsigned long long stash[BLOCK * SLOTS];
    __shared__ float candVal[CAP];
    __shared__ int   candIdx[CAP];
    __shared__ float selVal[128];
    __shared__ int   selIdx[128];
    __shared__ float red[4], redM[4], redS[4], redT[4];
    __shared__ int s_wcnt[4];
    __shared__ int s_flag;
    __shared__ int s_candCount, s_selCount;
    __shared__ unsigned s_lowBound, s_countGE, s_cGT;
    __shared__ int s_shift;

    // Early label fetch (latency hidden under pass A).
    int lab = 0; bool valid = false; float sl = 0.0f;
    if (tid == 0) {
        s_flag = 0;
        lab = L[tok];
        valid = (lab != IGNORE_INDEX);
        if (valid && lab >= 0 && lab < V) sl = srow[lab];
    }
    __syncthreads();

    // ---- Pass A state ----
    // Student LSE: sum = (a0+a1+a2+a3) * e^K.  K=0 normally; rare rescale
    // keeps every exp arg <= 60 so the f32 sum cannot overflow (<=8000*e^60).
    float K = 0.0f, Kp60 = 60.0f, mt = -INFINITY;
    float a0 = 0.f, a1 = 0.f, a2 = 0.f, a3 = 0.f;
    int cnt = 0;   // per-thread candidate count (may exceed SLOTS -> fallback)

#define S_RESCALE(nm)                                                     \
    do {                                                                  \
        float sc_ = __expf(K - (nm));                                     \
        a0 *= sc_; a1 *= sc_; a2 *= sc_; a3 *= sc_;                       \
        K = (nm); Kp60 = K + 60.0f;                                       \
    } while (0)

#define S_STEP(sv)                                                        \
    do {                                                                  \
        float smx_ = fmaxf(fmaxf((sv).x, (sv).y), fmaxf((sv).z, (sv).w));\
        mt = fmaxf(mt, smx_);                                             \
        if (smx_ > Kp60) S_RESCALE(smx_);                                 \
        a0 += __expf((sv).x - K);                                         \
        a1 += __expf((sv).y - K);                                         \
        a2 += __expf((sv).z - K);                                         \
        a3 += __expf((sv).w - K);                                         \
    } while (0)

#define STASH1(v, idx)                                                    \
    do {                                                                  \
        if ((v) >= SPEC_TH) {                                             \
            if (cnt < SLOTS)                                              \
                stash[tid * SLOTS + cnt] =                                \
                    ((unsigned long long)(unsigned)(idx) << 32) |         \
                    (unsigned long long)__float_as_uint(v);               \
            ++cnt;                                                        \
        }                                                                 \
    } while (0)

#define T_STEP(tv, ebase)                                                 \
    do {                                                                  \
        float tmx_ = fmaxf(fmaxf((tv).x, (tv).y), fmaxf((tv).z, (tv).w));\
        if (tmx_ >= SPEC_TH) {                                            \
            STASH1((tv).x, (ebase));                                      \
            STASH1((tv).y, (ebase) + 1);                                  \
            STASH1((tv).z, (ebase) + 2);                                  \
            STASH1((tv).w, (ebase) + 3);                                  \
        }                                                                 \
    } while (0)

    const int V4 = V >> 2;
    const float4* s4 = (const float4*)srow;
    const float4* t4 = (const float4*)trow;
    const int NB = V4 / BLOCK;

    // ---- software-pipelined main loop: 4 slots, prefetch distance 4.
    //      At every consume point 6-8 global loads stay outstanding.
    float4 SV0, SV1, SV2, SV3, TV0, TV1, TV2, TV3;
#define LOADSLOT(u, bb)                                                   \
    do { int i_ = (bb) * BLOCK + tid; SV##u = s4[i_]; TV##u = t4[i_]; } while (0)
#define PROC(u, bb)                                                       \
    do { int eb_ = (((bb) * BLOCK + tid) << 2);                           \
         S_STEP(SV##u); T_STEP(TV##u, eb_); } while (0)

    int b = 0;
    if (NB >= 8) {
        LOADSLOT(0, 0); LOADSLOT(1, 1); LOADSLOT(2, 2); LOADSLOT(3, 3);
#pragma unroll 1
        for (; b + 8 <= NB; b += 4) {
            PROC(0, b);     LOADSLOT(0, b + 4);
            PROC(1, b + 1); LOADSLOT(1, b + 5);
            PROC(2, b + 2); LOADSLOT(2, b + 6);
            PROC(3, b + 3); LOADSLOT(3, b + 7);
        }
        PROC(0, b); PROC(1, b + 1); PROC(2, b + 2); PROC(3, b + 3);
        b += 4;
    }
#pragma unroll 1
    for (; b < NB; ++b) { LOADSLOT(0, b); PROC(0, b); }
    // float4 tail
    for (int i = NB * BLOCK + tid; i < V4; i += BLOCK) {
        float4 sv = s4[i]; float4 tv = t4[i];
        int eb = i << 2;
        S_STEP(sv); T_STEP(tv, eb);
    }
    // scalar remainder (V % 4)
    for (int j = (V4 << 2) + tid; j < V; j += BLOCK) {
        float v = srow[j];
        mt = fmaxf(mt, v);
        if (v > Kp60) S_RESCALE(v);
        a0 += __expf(v - K);
        float tv = trow[j];
        STASH1(tv, j);
    }

    // ---- per-thread reduce + wave reduce ----
    float sAll = (a0 + a1) + (a2 + a3);

    // candidate-count inclusive scan within wave
    int inc = cnt;
    for (int off = 1; off < 64; off <<= 1) {
        int t = __shfl_up(inc, off);
        if (lane >= off) inc += t;
    }
    if (cnt > SLOTS) s_flag = 1;            // rare; benign race (set-to-1 only)
    if (lane == 63) s_wcnt[wid] = inc;

    // (K, s, mt) wave merge — representation-agnostic pair merge
    float mK = K, mS = sAll, mT = mt;
    for (int off = 32; off; off >>= 1) {
        float ko = __shfl_down(mK, off);
        float so = __shfl_down(mS, off);
        float to = __shfl_down(mT, off);
        float mn = fmaxf(mK, ko);
        mS = mS * __expf(mK - mn) + so * __expf(ko - mn);
        mK = mn;
        mT = fmaxf(mT, to);
    }
    if (lane == 0) { redM[wid] = mK; redS[wid] = mS; redT[wid] = mT; }
    __syncthreads();   // closes stash writes + s_wcnt + s_flag + red*

    float nll = 0.0f;
    if (tid == 0) {
        float mm = redM[0], ss = redS[0], tt = redT[0];
        for (int w = 1; w < 4; ++w) {
            float mn = fmaxf(mm, redM[w]);
            ss = ss * __expf(mm - mn) + redS[w] * __expf(redM[w] - mn);
            mm = mn;
            tt = fmaxf(tt, redT[w]);
        }
        float lse = (ss > 0.0f) ? (mm + __logf(ss)) : tt;   // underflow guard
        nll = lse - sl;   // -log_softmax at label
    }

    const int c0 = s_wcnt[0], c1 = s_wcnt[1], c2 = s_wcnt[2], c3 = s_wcnt[3];
    const int total = c0 + c1 + c2 + c3;
    const bool fast = (!s_flag) && (total >= KTOP) && (total <= CAP);

    if (fast) {
        // compact per-thread stashes into a contiguous candidate list
        int base0 = 0;
        if (wid > 0) base0 += c0;
        if (wid > 1) base0 += c1;
        if (wid > 2) base0 += c2;
        const int myoff = base0 + inc - cnt;   // exclusive prefix
        for (int r = 0; r < cnt; ++r) {
            unsigned long long e = stash[tid * SLOTS + r];
            candVal[myoff + r] = __uint_as_float((unsigned)e);
            candIdx[myoff + r] = (int)(e >> 32);
        }
        if (tid == 0) s_candCount = total;
        __syncthreads();
    } else {
        // ---- exact radix-select fallback (arbitrary data); hist aliases stash
        unsigned* hist = (unsigned*)stash;
        unsigned* chunkp = ((unsigned*)stash) + NHIST;
        for (int h = tid; h < NHIST; h += BLOCK) hist[h] = 0;
        if (tid == 0) s_candCount = 0;
        __syncthreads();
        for (int p = tid; p < V; p += BLOCK)
            atomicAdd(&hist[key_of(trow[p]) >> 23], 1u);
        __syncthreads();
        if (tid < 64) {
            unsigned cs = 0;
            for (int h = tid * 8; h < tid * 8 + 8; ++h) cs += hist[h];
            chunkp[tid] = cs;
        }
        __syncthreads();
        if (tid == 0) {
            unsigned accum = 0; int csel = 0;
            for (int c = 63; c >= 0; --c) {
                if (accum + chunkp[c] >= (unsigned)KTOP) { csel = c; break; }
                accum += chunkp[c];
            }
            int bsel = csel * 8;
            for (int h = csel * 8 + 7; h >= csel * 8; --h) {
                if (accum + hist[h] >= (unsigned)KTOP) { bsel = h; break; }
                accum += hist[h];
            }
            s_cGT = accum;
            s_countGE = accum + hist[bsel];
            s_lowBound = (unsigned)bsel << 23;
            s_shift = 23;
        }
        while (true) {
            __syncthreads();
            if (s_countGE <= (unsigned)CAP || s_shift == 0) break;
            const int shift = s_shift;
            const int nextShift = (shift >= 9) ? (shift - 9) : 0;
            const int nb = 1 << (shift - nextShift);
            const unsigned prefix = s_lowBound >> shift;
            const unsigned cGT_in = s_cGT;
            __syncthreads();
            for (int h = tid; h < nb; h += BLOCK) hist[h] = 0;
            __syncthreads();
            for (int p = tid; p < V; p += BLOCK) {
                unsigned key = key_of(trow[p]);
                if ((key >> shift) == prefix)
                    atomicAdd(&hist[(key >> nextShift) & (nb - 1)], 1u);
            }
            __syncthreads();
            if (tid == 0) {
                unsigned kRem = (unsigned)KTOP - cGT_in;
                unsigned accum = 0; int bsel = 0;
                for (int h = nb - 1; h >= 0; --h) {
                    if (accum + hist[h] >= kRem) { bsel = h; break; }
                    accum += hist[h];
                }
                s_cGT = cGT_in + accum;
                s_countGE = s_cGT + hist[bsel];
                s_lowBound |= (unsigned)bsel << nextShift;
                s_shift = nextShift;
            }
        }
        __syncthreads();
        const unsigned lowB = s_lowBound;
        for (int p = tid; p < V; p += BLOCK) {
            float v = trow[p];
            if (key_of(v) >= lowB) {
                int q = atomicAdd(&s_candCount, 1);
                if (q < CAP) { candVal[q] = v; candIdx[q] = p; }
            }
        }
        __syncthreads();
    }

    // ---- exact top-K among M candidates via O(M^2) ranking (idx tie-break) ----
    const int M = min(s_candCount, CAP);
    if (tid == 0) s_selCount = 0;
    __syncthreads();
    for (int c = tid; c < M; c += BLOCK) {
        float vc = candVal[c]; int ic = candIdx[c];
        int rank = 0;
        for (int j = 0; j < M; ++j) {
            float vj = candVal[j]; int ij = candIdx[j];
            if (vj > vc || (vj == vc && ij < ic)) ++rank;
        }
        if (rank < KTOP) {
            int p = atomicAdd(&s_selCount, 1);
            if (p < 128) { selVal[p] = vc; selIdx[p] = ic; }
        }
    }
    __syncthreads();
    const int n = min(s_selCount, 128);

    // ---- temperature KL over the selected top-K ----
    float x = -INFINITY, y = -INFINITY;
    if (tid < n) {
        x = selVal[tid] * (1.0f / TEMP);
        y = srow[selIdx[tid]] * (1.0f / TEMP);
    }
    float mx = block_max(x, red);
    float my = block_max(y, red);
    float ex = (tid < n) ? __expf(x - mx) : 0.0f;
    float Zt = block_sum(ex, red);
    float ey = (tid < n) ? __expf(y - my) : 0.0f;
    float Zs = block_sum(ey, red);
    float lZt = __logf(Zt), lZs = __logf(Zs);
    float kli = (tid < n) ? (ex / Zt) * ((x - mx - lZt) - (y - my - lZs)) : 0.0f;
    float kl = block_sum(kli, red);

    if (tid == 0 && valid) {
        atomicAdd(&acc[0], nll);
        atomicAdd(&acc[1], kl);
        atomicAdd(&acc[2], 1.0f);
    }
}

__global__ void tcs_finalize(const float* __restrict__ acc, float* __restrict__ out) {
    float cnt = fmaxf(acc[2], 1.0f);
    float ce = acc[0] / cnt;
    float tcs = acc[1] / cnt * (TEMP * TEMP);
    out[0] = ce + LAMBDA_TCS * tcs;
    out[1] = ce;
    out[2] = tcs;
    out[3] = 0.0f;
}

extern "C" void kernel_launch(void* const* d_in, const int* in_sizes, int n_in,
                              void* d_out, int out_size, void* d_ws, size_t ws_size,
                              hipStream_t stream) {
    const float* S = (const float*)d_in[0];
    const float* T = (const float*)d_in[1];
    const int* L = (const int*)d_in[2];
    const int tokens = in_sizes[2];
    const int V = in_sizes[0] / tokens;
    float* acc = (float*)d_ws;
    hipMemsetAsync(acc, 0, 4 * sizeof(float), stream);
    tcs_main<<<tokens, BLOCK, 0, stream>>>(S, T, L, acc, V, tokens);
    tcs_finalize<<<1, 1, 0, stream>>>(acc, (float*)d_out);
}